// Round 11
// baseline (118.532 us; speedup 1.0000x reference)
//
#include <hip/hip_runtime.h>

#define CHVOL (128*128*128)

// 9 stats: [S_-2, S_-1, S_0(count), S_1, S_2, S_3, S_4, S_5, T=sum x*ln x]
__device__ __forceinline__ void accum9(float* a, float x) {
    bool nz = (x != 0.0f);
    float u = nz ? __builtin_amdgcn_rcpf(x) : 0.0f;
    float l = nz ? __logf(x) : 0.0f;
    float x2 = x * x;
    float x4 = x2 * x2;
    a[0] = fmaf(u, u, a[0]);
    a[1] += u;
    a[2] += nz ? 1.0f : 0.0f;
    a[3] += x;
    a[4] += x2;
    a[5] = fmaf(x2, x, a[5]);
    a[6] += x4;
    a[7] = fmaf(x4, x, a[7]);
    a[8] = fmaf(x, l, a[8]);
}

// In-wave reduce of NS stats; lane 0 of each wave holds the wave total.
template<int NS>
__device__ __forceinline__ void wave_reduce(float* acc) {
    #pragma unroll
    for (int s = 0; s < NS; ++s) {
        float v = acc[s];
        v += __shfl_down(v, 32, 64);
        v += __shfl_down(v, 16, 64);
        v += __shfl_down(v, 8, 64);
        v += __shfl_down(v, 4, 64);
        v += __shfl_down(v, 2, 64);
        v += __shfl_down(v, 1, 64);
        acc[s] = v;
    }
}

template<int NS>
__device__ __forceinline__ void block_reduce(float* acc, float* red, int t) {
    #pragma unroll
    for (int s = 0; s < NS; ++s) {
        float v = acc[s];
        v += __shfl_down(v, 32, 64);
        v += __shfl_down(v, 16, 64);
        v += __shfl_down(v, 8, 64);
        v += __shfl_down(v, 4, 64);
        v += __shfl_down(v, 2, 64);
        v += __shfl_down(v, 1, 64);
        if ((t & 63) == 0) red[(t >> 6) * NS + s] = v;
    }
    __syncthreads();
}

// ===== PRODUCER =====
// 512 workgroups (2 per CU, balanced) instead of 1536: CP dispatches WGs at
// ~30 ns each, so 1536 WGs cost ~46 us of dispatch serialization — that was
// k_main's hidden floor (fits rounds 0-10: fused 56 us = 46 + spin-tail;
// R9's 384-WG/512t = 12 + 2-block imbalance; occupancy time-avg 16-26%).
// Each block processes its 128(x) x 8(y) x 8(z) region for THREE channels
// (blockIdx.y = channel group), body per channel identical to round 0/6/10.
__global__ __launch_bounds__(256) void k_main(const float* __restrict__ img,
                                              float* __restrict__ part,
                                              float* __restrict__ l3map) {
    __shared__ float zm[256];        // [w4][z''2][x32]
    __shared__ float red[36 * 4];

    const int t  = threadIdx.x;
    const int l  = t & 63, w = t >> 6;
    const int r  = blockIdx.x;        // 0..255 (region)
    const int cg = blockIdx.y;        // 0..1 (channel group of 3)
    const int ry = r & 15, rz = r >> 4;
    const int x5 = l & 31;
    const int y  = ((l >> 5) & 1) | (w << 1);   // y in [0,8)

    for (int cc = 0; cc < 3; ++cc) {
        const int ch = cg * 3 + cc;   // 0..5
        const float* tbase = img + (size_t)ch * CHVOL + rz * (8 * 16384)
                           + ry * (8 * 128) + y * 128 + x5 * 4;

        float acc[36];
        #pragma unroll
        for (int j = 0; j < 36; ++j) acc[j] = 0.0f;

        // Prefetch all 8 z-slice float4s (8-deep MLP per wave).
        float4 v[8];
        #pragma unroll
        for (int i = 0; i < 8; ++i) v[i] = *(const float4*)(tbase + i * 16384);

        float d0 = 0.0f, d1 = 0.0f;
        float ca = 0.0f, cb = 0.0f;
        #pragma unroll
        for (int i = 0; i < 8; ++i) {
            accum9(acc, v[i].x); accum9(acc, v[i].y); accum9(acc, v[i].z); accum9(acc, v[i].w);
            float a = v[i].x + v[i].y, b = v[i].z + v[i].w;
            a += __shfl_xor(a, 32, 64);            // y-pair merge
            b += __shfl_xor(b, 32, 64);
            if ((i & 1) == 0) { ca = a; cb = b; }
            else {
                float A = ca + a, B = cb + b;      // L1 cells
                accum9(acc + 9, A); accum9(acc + 9, B);
                if (i < 4) d0 += A + B; else d1 += A + B;
            }
        }
        #pragma unroll
        for (int j = 9; j < 18; ++j) acc[j] *= 0.5f;   // L1 replicated on y-lane pairs

        if ((l >> 5) == 0) {             // one writer per replica pair
            zm[w * 64 + x5]      = d0;
            zm[w * 64 + 32 + x5] = d1;
        }
        __syncthreads();                 // also protects zm vs previous iteration

        // L2: 32(x) x 2(y'') x 2(z'')
        if (t < 128) {
            int x = t & 31, zpp = (t >> 5) & 1, ypp = t >> 6;
            float s = zm[(2 * ypp) * 64 + zpp * 32 + x] + zm[(2 * ypp + 1) * 64 + zpp * 32 + x];
            accum9(acc + 18, s);
        }
        // L3: 16 cells per region
        if (t < 16) {
            float s = 0.0f;
            #pragma unroll
            for (int q = 0; q < 8; ++q)
                s += zm[q * 32 + 2 * t] + zm[q * 32 + 2 * t + 1];
            accum9(acc + 27, s);
            l3map[(size_t)ch * 4096 + rz * 256 + ry * 16 + t] = s;
        }

        block_reduce<36>(acc, red, t);   // internal sync protects red reuse
        if (t < 36)
            part[((size_t)ch * 36 + t) * 256 + r] =
                red[t] + red[36 + t] + red[72 + t] + red[108 + t];
    }
}

// ===== CONSUMER: unchanged from round 10 (lean, 6 blocks, ~5 us) =====
__global__ __launch_bounds__(512) void k_fin(const float* __restrict__ part,
                                             const float* __restrict__ l3map,
                                             const int* __restrict__ bounds,
                                             float* __restrict__ out) {
    __shared__ float M4[512];
    __shared__ float redA[36 * 4];
    __shared__ float redB[9 * 4];
    __shared__ float sst[54];

    const int t  = threadIdx.x;
    const int ch = blockIdx.x;

    if (t < 256) {
        // levels 0-3 from block partials (coalesced, 1 load/thread/stat)
        float acc[36];
        #pragma unroll
        for (int j = 0; j < 36; ++j)
            acc[j] = part[((size_t)ch * 36 + j) * 256 + t];
        wave_reduce<36>(acc);
        if ((t & 63) == 0) {
            #pragma unroll
            for (int s = 0; s < 36; ++s) redA[(t >> 6) * 36 + s] = acc[s];
        }
    } else {
        // level 4: pool l3map 16^3 -> 8^3, two cells per thread
        const float2* L3 = (const float2*)(l3map + (size_t)ch * 4096);
        const int th = t - 256;
        float a9[9];
        #pragma unroll
        for (int j = 0; j < 9; ++j) a9[j] = 0.0f;
        #pragma unroll
        for (int i = 0; i < 2; ++i) {
            int c = th + i * 256;
            int x = c & 7, y = (c >> 3) & 7, z = c >> 6;
            const float2* p = L3 + z * 256 + y * 16 + x;   // f2 idx = 2z*128+2y*8+x
            float2 b0 = p[0], b1 = p[8], b2 = p[128], b3 = p[136];
            float s = (b0.x + b0.y) + (b1.x + b1.y) + (b2.x + b2.y) + (b3.x + b3.y);
            M4[c] = s;
            accum9(a9, s);
        }
        wave_reduce<9>(a9);
        if ((t & 63) == 0) {
            #pragma unroll
            for (int s = 0; s < 9; ++s) redB[((t >> 6) - 4) * 9 + s] = a9[s];
        }
    }
    __syncthreads();

    if (t < 36) sst[t] = redA[t] + redA[36 + t] + redA[72 + t] + redA[108 + t];
    if (t >= 36 && t < 45) {
        int s = t - 36;
        sst[36 + s] = redB[s] + redB[9 + s] + redB[18 + s] + redB[27 + s];
    }
    if (t < 64) {
        float c9[9];
        #pragma unroll
        for (int j = 0; j < 9; ++j) c9[j] = 0.0f;
        int x = t & 3, y = (t >> 2) & 3, z = t >> 4;
        const float2* p = (const float2*)M4 + z * 64 + y * 8 + x;  // 2z*32+2y*4+x
        float2 b0 = p[0], b1 = p[4], b2 = p[32], b3 = p[36];
        float s = (b0.x + b0.y) + (b1.x + b1.y) + (b2.x + b2.y) + (b3.x + b3.y);
        accum9(c9, s);
        wave_reduce<9>(c9);
        if (t == 0) {
            #pragma unroll
            for (int j = 0; j < 9; ++j) sst[45 + j] = c9[j];
        }
    }
    __syncthreads();

    // finale: least-squares slope, double precision, 8 outputs
    if (t < 8) {
        int k = bounds[t];
        const double LN2 = 0.6931471805599453094;
        double b  = (double)sst[3];          // S_1 at level 0 == total sum
        double lb = log(b);
        double num = 0.0;
        #pragma unroll
        for (int s = 0; s < 6; ++s) {
            const float* st = sst + s * 9;
            double p;
            if (k == 1) p = ((double)st[8] - lb * (double)st[3]) / b;
            else        p = log((double)st[k + 2]) - (double)k * lb;
            num += (6.0 * s - 15.0) * LN2 * p;   // n*q_s - qs
        }
        double den = 105.0 * LN2 * LN2;          // n*q2s - qs^2
        double aa  = (k == 1) ? 1.0 : 1.0 / (double)(k - 1);
        out[ch * 8 + t] = (float)(aa * num / den);
    }
}

extern "C" void kernel_launch(void* const* d_in, const int* in_sizes, int n_in,
                              void* d_out, int out_size, void* d_ws, size_t ws_size,
                              hipStream_t stream) {
    const float* img    = (const float*)d_in[0];
    const int*   bounds = (const int*)d_in[1];
    float*       out    = (float*)d_out;
    float*       ws     = (float*)d_ws;

    // ws layout (floats): part[6*36*256=55296] @0, l3map[6*4096=24576] @55296.
    float* part  = ws;
    float* l3map = ws + 55296;

    k_main<<<dim3(256, 2), 256, 0, stream>>>(img, part, l3map);
    k_fin<<<6, 512, 0, stream>>>(part, l3map, bounds, out);
}

// Round 13
// 115.313 us; speedup vs baseline: 1.0279x; 1.0279x over previous
//
#include <hip/hip_runtime.h>

#define CHVOL (128*128*128)

// 9 stats: [S_-2, S_-1, S_0(count), S_1, S_2, S_3, S_4, S_5, T=sum x*ln x]
__device__ __forceinline__ void accum9(float* a, float x) {
    bool nz = (x != 0.0f);
    float u = nz ? __builtin_amdgcn_rcpf(x) : 0.0f;
    float l = nz ? __logf(x) : 0.0f;
    float x2 = x * x;
    float x4 = x2 * x2;
    a[0] = fmaf(u, u, a[0]);
    a[1] += u;
    a[2] += nz ? 1.0f : 0.0f;
    a[3] += x;
    a[4] += x2;
    a[5] = fmaf(x2, x, a[5]);
    a[6] += x4;
    a[7] = fmaf(x4, x, a[7]);
    a[8] = fmaf(x, l, a[8]);
}

// In-wave reduce of NS stats; lane 0 of each wave holds the wave total.
template<int NS>
__device__ __forceinline__ void wave_reduce(float* acc) {
    #pragma unroll
    for (int s = 0; s < NS; ++s) {
        float v = acc[s];
        v += __shfl_down(v, 32, 64);
        v += __shfl_down(v, 16, 64);
        v += __shfl_down(v, 8, 64);
        v += __shfl_down(v, 4, 64);
        v += __shfl_down(v, 2, 64);
        v += __shfl_down(v, 1, 64);
        acc[s] = v;
    }
}

template<int NS>
__device__ __forceinline__ void block_reduce(float* acc, float* red, int t) {
    #pragma unroll
    for (int s = 0; s < NS; ++s) {
        float v = acc[s];
        v += __shfl_down(v, 32, 64);
        v += __shfl_down(v, 16, 64);
        v += __shfl_down(v, 8, 64);
        v += __shfl_down(v, 4, 64);
        v += __shfl_down(v, 2, 64);
        v += __shfl_down(v, 1, 64);
        if ((t & 63) == 0) red[(t >> 6) * NS + s] = v;
    }
    __syncthreads();
}

// ===== PRODUCER: in-thread pyramid, zero inner-loop cross-lane ops =====
// Region = 128(x) x 8(y) x 8(z). Thread (x5,yp,zq) owns a 4x * 2y * 4z brick:
// 8 float4 loads (same 8-deep MLP / coalescing as before). Its 4 L1 cells
// (2x2x2) are pure in-register sums: no shfl_xor, no lane replication, no
// *0.5 fixup (round 11's k_main spent ~70% stalled; the 16 cross-lane ops
// per channel on the accum9 critical path are the prime suspect).
// The thread's brick sum p goes to zm[yp][zq][x5] -- IDENTICAL layout to the
// proven kernel's d-values, so L2/L3/block_reduce/store are verbatim.
__global__ __launch_bounds__(256) void k_main(const float* __restrict__ img,
                                              float* __restrict__ part,
                                              float* __restrict__ l3map) {
    __shared__ float zm[256];        // [yp 4][zq 2][x5 32]
    __shared__ float red[36 * 4];

    const int t  = threadIdx.x;
    const int r  = blockIdx.x;        // 0..255
    const int ch = blockIdx.y;        // 0..5
    const int ry = r & 15, rz = r >> 4;

    const int x5 = t & 31;            // x = 4*x5 .. 4*x5+3
    const int yp = (t >> 5) & 3;      // y = 2*yp, 2*yp+1
    const int zq = t >> 7;            // z = 4*zq .. 4*zq+3

    const float* tb = img + (size_t)ch * CHVOL + rz * (8 * 16384) + ry * (8 * 128)
                    + (zq * 4) * 16384 + (yp * 2) * 128 + x5 * 4;

    float acc[36];
    #pragma unroll
    for (int j = 0; j < 36; ++j) acc[j] = 0.0f;

    // 8 loads: v[dz*2+dy], all issued up-front (8-deep MLP).
    float4 v[8];
    #pragma unroll
    for (int dz = 0; dz < 4; ++dz)
        #pragma unroll
        for (int dy = 0; dy < 2; ++dy)
            v[dz * 2 + dy] = *(const float4*)(tb + dz * 16384 + dy * 128);

    // L0: every voxel.
    #pragma unroll
    for (int i = 0; i < 8; ++i) {
        accum9(acc, v[i].x); accum9(acc, v[i].y); accum9(acc, v[i].z); accum9(acc, v[i].w);
    }

    // L1: x-pair -> y-pair -> z-pair trees (same order as before, in-thread).
    float ax[8], bx[8];
    #pragma unroll
    for (int i = 0; i < 8; ++i) { ax[i] = v[i].x + v[i].y; bx[i] = v[i].z + v[i].w; }
    float A0 = (ax[0] + ax[1]) + (ax[2] + ax[3]);   // (x=4x5..+1, y-pair, z-pair dz0-1)
    float B0 = (bx[0] + bx[1]) + (bx[2] + bx[3]);   // (x=4x5+2..+3, ...)
    float A1 = (ax[4] + ax[5]) + (ax[6] + ax[7]);   // dz2-3
    float B1 = (bx[4] + bx[5]) + (bx[6] + bx[7]);
    accum9(acc + 9, A0); accum9(acc + 9, B0); accum9(acc + 9, A1); accum9(acc + 9, B1);

    // Thread's 4x2x4 brick sum: x-merge then z-merge (matches old d0 tree).
    zm[yp * 64 + zq * 32 + x5] = (A0 + B0) + (A1 + B1);
    __syncthreads();

    // L2: 32(x) x 2(y'') x 2(z'') -- verbatim from the proven kernel.
    if (t < 128) {
        int x = t & 31, zpp = (t >> 5) & 1, ypp = t >> 6;
        float s = zm[(2 * ypp) * 64 + zpp * 32 + x] + zm[(2 * ypp + 1) * 64 + zpp * 32 + x];
        accum9(acc + 18, s);
    }
    // L3: 16 cells -- verbatim.
    if (t < 16) {
        float s = 0.0f;
        #pragma unroll
        for (int q = 0; q < 8; ++q)
            s += zm[q * 32 + 2 * t] + zm[q * 32 + 2 * t + 1];
        accum9(acc + 27, s);
        l3map[(size_t)ch * 4096 + rz * 256 + ry * 16 + t] = s;
    }

    block_reduce<36>(acc, red, t);
    if (t < 36)
        part[((size_t)ch * 36 + t) * 256 + r] =
            red[t] + red[36 + t] + red[72 + t] + red[108 + t];
}

// ===== CONSUMER: unchanged from round 10 (lean, 6 blocks, ~5 us) =====
__global__ __launch_bounds__(512) void k_fin(const float* __restrict__ part,
                                             const float* __restrict__ l3map,
                                             const int* __restrict__ bounds,
                                             float* __restrict__ out) {
    __shared__ float M4[512];
    __shared__ float redA[36 * 4];
    __shared__ float redB[9 * 4];
    __shared__ float sst[54];

    const int t  = threadIdx.x;
    const int ch = blockIdx.x;

    if (t < 256) {
        float acc[36];
        #pragma unroll
        for (int j = 0; j < 36; ++j)
            acc[j] = part[((size_t)ch * 36 + j) * 256 + t];
        wave_reduce<36>(acc);
        if ((t & 63) == 0) {
            #pragma unroll
            for (int s = 0; s < 36; ++s) redA[(t >> 6) * 36 + s] = acc[s];
        }
    } else {
        const float2* L3 = (const float2*)(l3map + (size_t)ch * 4096);
        const int th = t - 256;
        float a9[9];
        #pragma unroll
        for (int j = 0; j < 9; ++j) a9[j] = 0.0f;
        #pragma unroll
        for (int i = 0; i < 2; ++i) {
            int c = th + i * 256;
            int x = c & 7, y = (c >> 3) & 7, z = c >> 6;
            const float2* p = L3 + z * 256 + y * 16 + x;   // f2 idx = 2z*128+2y*8+x
            float2 b0 = p[0], b1 = p[8], b2 = p[128], b3 = p[136];
            float s = (b0.x + b0.y) + (b1.x + b1.y) + (b2.x + b2.y) + (b3.x + b3.y);
            M4[c] = s;
            accum9(a9, s);
        }
        wave_reduce<9>(a9);
        if ((t & 63) == 0) {
            #pragma unroll
            for (int s = 0; s < 9; ++s) redB[((t >> 6) - 4) * 9 + s] = a9[s];
        }
    }
    __syncthreads();

    if (t < 36) sst[t] = redA[t] + redA[36 + t] + redA[72 + t] + redA[108 + t];
    if (t >= 36 && t < 45) {
        int s = t - 36;
        sst[36 + s] = redB[s] + redB[9 + s] + redB[18 + s] + redB[27 + s];
    }
    if (t < 64) {
        float c9[9];
        #pragma unroll
        for (int j = 0; j < 9; ++j) c9[j] = 0.0f;
        int x = t & 3, y = (t >> 2) & 3, z = t >> 4;
        const float2* p = (const float2*)M4 + z * 64 + y * 8 + x;  // 2z*32+2y*4+x
        float2 b0 = p[0], b1 = p[4], b2 = p[32], b3 = p[36];
        float s = (b0.x + b0.y) + (b1.x + b1.y) + (b2.x + b2.y) + (b3.x + b3.y);
        accum9(c9, s);
        wave_reduce<9>(c9);
        if (t == 0) {
            #pragma unroll
            for (int j = 0; j < 9; ++j) sst[45 + j] = c9[j];
        }
    }
    __syncthreads();

    if (t < 8) {
        int k = bounds[t];
        const double LN2 = 0.6931471805599453094;
        double b  = (double)sst[3];          // S_1 at level 0 == total sum
        double lb = log(b);
        double num = 0.0;
        #pragma unroll
        for (int s = 0; s < 6; ++s) {
            const float* st = sst + s * 9;
            double p;
            if (k == 1) p = ((double)st[8] - lb * (double)st[3]) / b;
            else        p = log((double)st[k + 2]) - (double)k * lb;
            num += (6.0 * s - 15.0) * LN2 * p;   // n*q_s - qs
        }
        double den = 105.0 * LN2 * LN2;          // n*q2s - qs^2
        double aa  = (k == 1) ? 1.0 : 1.0 / (double)(k - 1);
        out[ch * 8 + t] = (float)(aa * num / den);
    }
}

extern "C" void kernel_launch(void* const* d_in, const int* in_sizes, int n_in,
                              void* d_out, int out_size, void* d_ws, size_t ws_size,
                              hipStream_t stream) {
    const float* img    = (const float*)d_in[0];
    const int*   bounds = (const int*)d_in[1];
    float*       out    = (float*)d_out;
    float*       ws     = (float*)d_ws;

    // ws layout (floats): part[6*36*256=55296] @0, l3map[6*4096=24576] @55296.
    float* part  = ws;
    float* l3map = ws + 55296;

    k_main<<<dim3(256, 6), 256, 0, stream>>>(img, part, l3map);
    k_fin<<<6, 512, 0, stream>>>(part, l3map, bounds, out);
}

// Round 14
// 97.646 us; speedup vs baseline: 1.2139x; 1.1809x over previous
//
#include <hip/hip_runtime.h>

#define CHVOL (128*128*128)

// 9 stats: [S_-2, S_-1, S_0(count), S_1, S_2, S_3, S_4, S_5, T=sum x*ln x]
__device__ __forceinline__ void accum9(float* a, float x) {
    bool nz = (x != 0.0f);
    float u = nz ? __builtin_amdgcn_rcpf(x) : 0.0f;
    float l = nz ? __logf(x) : 0.0f;
    float x2 = x * x;
    float x4 = x2 * x2;
    a[0] = fmaf(u, u, a[0]);
    a[1] += u;
    a[2] += nz ? 1.0f : 0.0f;
    a[3] += x;
    a[4] += x2;
    a[5] = fmaf(x2, x, a[5]);
    a[6] += x4;
    a[7] = fmaf(x4, x, a[7]);
    a[8] = fmaf(x, l, a[8]);
}

// DPP wave-64 sum (rocPRIM idiom): 6 VALU adds, ZERO LDS-pipe traffic.
// Replaces 6 ds_bpermute per stat (R13 counters: 216 bpermute/wave = ~15 us
// of per-CU-serialized LDS pipe — the hidden k_main floor). Total in lane 63.
template<int CTRL, int RMASK>
__device__ __forceinline__ float dppadd(float x) {
    int y = __builtin_amdgcn_update_dpp(0, __float_as_int(x), CTRL, RMASK, 0xf, true);
    return x + __int_as_float(y);
}
__device__ __forceinline__ float wave_sum_dpp(float v) {
    v = dppadd<0x111, 0xf>(v);   // row_shr:1
    v = dppadd<0x112, 0xf>(v);   // row_shr:2
    v = dppadd<0x114, 0xf>(v);   // row_shr:4
    v = dppadd<0x118, 0xf>(v);   // row_shr:8  -> lane15 of each row = row sum
    v = dppadd<0x142, 0xa>(v);   // row_bcast:15 -> rows 1,3
    v = dppadd<0x143, 0xc>(v);   // row_bcast:31 -> rows 2,3; lane 63 = total
    return v;
}

// Block reduce via DPP: per-wave totals (lane 63) -> red[w*NS+s], sync.
template<int NS>
__device__ __forceinline__ void block_reduce(float* acc, float* red, int t) {
    #pragma unroll
    for (int s = 0; s < NS; ++s) {
        float v = wave_sum_dpp(acc[s]);
        if ((t & 63) == 63) red[(t >> 6) * NS + s] = v;
    }
    __syncthreads();
}

// ===== PRODUCER: in-thread pyramid (R13) + DPP block reduction =====
// Region = 128(x) x 8(y) x 8(z). Thread (x5,yp,zq) owns a 4x*2y*4z brick.
__global__ __launch_bounds__(256) void k_main(const float* __restrict__ img,
                                              float* __restrict__ part,
                                              float* __restrict__ l3map) {
    __shared__ float zm[256];        // [yp 4][zq 2][x5 32]
    __shared__ float red[36 * 4];

    const int t  = threadIdx.x;
    const int r  = blockIdx.x;        // 0..255
    const int ch = blockIdx.y;        // 0..5
    const int ry = r & 15, rz = r >> 4;

    const int x5 = t & 31;            // x = 4*x5 .. 4*x5+3
    const int yp = (t >> 5) & 3;      // y = 2*yp, 2*yp+1
    const int zq = t >> 7;            // z = 4*zq .. 4*zq+3

    const float* tb = img + (size_t)ch * CHVOL + rz * (8 * 16384) + ry * (8 * 128)
                    + (zq * 4) * 16384 + (yp * 2) * 128 + x5 * 4;

    float acc[36];
    #pragma unroll
    for (int j = 0; j < 36; ++j) acc[j] = 0.0f;

    // 8 loads, all issued up-front (8-deep MLP).
    float4 v[8];
    #pragma unroll
    for (int dz = 0; dz < 4; ++dz)
        #pragma unroll
        for (int dy = 0; dy < 2; ++dy)
            v[dz * 2 + dy] = *(const float4*)(tb + dz * 16384 + dy * 128);

    // L0: every voxel.
    #pragma unroll
    for (int i = 0; i < 8; ++i) {
        accum9(acc, v[i].x); accum9(acc, v[i].y); accum9(acc, v[i].z); accum9(acc, v[i].w);
    }

    // L1: in-thread x-pair -> y-pair -> z-pair trees.
    float ax[8], bx[8];
    #pragma unroll
    for (int i = 0; i < 8; ++i) { ax[i] = v[i].x + v[i].y; bx[i] = v[i].z + v[i].w; }
    float A0 = (ax[0] + ax[1]) + (ax[2] + ax[3]);
    float B0 = (bx[0] + bx[1]) + (bx[2] + bx[3]);
    float A1 = (ax[4] + ax[5]) + (ax[6] + ax[7]);
    float B1 = (bx[4] + bx[5]) + (bx[6] + bx[7]);
    accum9(acc + 9, A0); accum9(acc + 9, B0); accum9(acc + 9, A1); accum9(acc + 9, B1);

    zm[yp * 64 + zq * 32 + x5] = (A0 + B0) + (A1 + B1);
    __syncthreads();

    // L2: 32(x) x 2(y'') x 2(z'')
    if (t < 128) {
        int x = t & 31, zpp = (t >> 5) & 1, ypp = t >> 6;
        float s = zm[(2 * ypp) * 64 + zpp * 32 + x] + zm[(2 * ypp + 1) * 64 + zpp * 32 + x];
        accum9(acc + 18, s);
    }
    // L3: 16 cells
    if (t < 16) {
        float s = 0.0f;
        #pragma unroll
        for (int q = 0; q < 8; ++q)
            s += zm[q * 32 + 2 * t] + zm[q * 32 + 2 * t + 1];
        accum9(acc + 27, s);
        l3map[(size_t)ch * 4096 + rz * 256 + ry * 16 + t] = s;
    }

    block_reduce<36>(acc, red, t);
    if (t < 36)
        part[((size_t)ch * 36 + t) * 256 + r] =
            red[t] + red[36 + t] + red[72 + t] + red[108 + t];
}

// ===== CONSUMER: lean (R10) with DPP wave sums =====
__global__ __launch_bounds__(512) void k_fin(const float* __restrict__ part,
                                             const float* __restrict__ l3map,
                                             const int* __restrict__ bounds,
                                             float* __restrict__ out) {
    __shared__ float M4[512];
    __shared__ float redA[36 * 4];
    __shared__ float redB[9 * 4];
    __shared__ float sst[54];

    const int t  = threadIdx.x;
    const int ch = blockIdx.x;

    if (t < 256) {
        float acc[36];
        #pragma unroll
        for (int j = 0; j < 36; ++j)
            acc[j] = part[((size_t)ch * 36 + j) * 256 + t];
        #pragma unroll
        for (int s = 0; s < 36; ++s) {
            float v = wave_sum_dpp(acc[s]);
            if ((t & 63) == 63) redA[(t >> 6) * 36 + s] = v;
        }
    } else {
        const float2* L3 = (const float2*)(l3map + (size_t)ch * 4096);
        const int th = t - 256;
        float a9[9];
        #pragma unroll
        for (int j = 0; j < 9; ++j) a9[j] = 0.0f;
        #pragma unroll
        for (int i = 0; i < 2; ++i) {
            int c = th + i * 256;
            int x = c & 7, y = (c >> 3) & 7, z = c >> 6;
            const float2* p = L3 + z * 256 + y * 16 + x;   // f2 idx = 2z*128+2y*8+x
            float2 b0 = p[0], b1 = p[8], b2 = p[128], b3 = p[136];
            float s = (b0.x + b0.y) + (b1.x + b1.y) + (b2.x + b2.y) + (b3.x + b3.y);
            M4[c] = s;
            accum9(a9, s);
        }
        #pragma unroll
        for (int s = 0; s < 9; ++s) {
            float v = wave_sum_dpp(a9[s]);
            if ((t & 63) == 63) redB[((t >> 6) - 4) * 9 + s] = v;
        }
    }
    __syncthreads();

    if (t < 36) sst[t] = redA[t] + redA[36 + t] + redA[72 + t] + redA[108 + t];
    if (t >= 36 && t < 45) {
        int s = t - 36;
        sst[36 + s] = redB[s] + redB[9 + s] + redB[18 + s] + redB[27 + s];
    }
    if (t < 64) {
        float c9[9];
        #pragma unroll
        for (int j = 0; j < 9; ++j) c9[j] = 0.0f;
        int x = t & 3, y = (t >> 2) & 3, z = t >> 4;
        const float2* p = (const float2*)M4 + z * 64 + y * 8 + x;  // 2z*32+2y*4+x
        float2 b0 = p[0], b1 = p[4], b2 = p[32], b3 = p[36];
        float s = (b0.x + b0.y) + (b1.x + b1.y) + (b2.x + b2.y) + (b3.x + b3.y);
        accum9(c9, s);
        #pragma unroll
        for (int j = 0; j < 9; ++j) {
            float v = wave_sum_dpp(c9[j]);
            if (t == 63) sst[45 + j] = v;
        }
    }
    __syncthreads();

    if (t < 8) {
        int k = bounds[t];
        const double LN2 = 0.6931471805599453094;
        double b  = (double)sst[3];          // S_1 at level 0 == total sum
        double lb = log(b);
        double num = 0.0;
        #pragma unroll
        for (int s = 0; s < 6; ++s) {
            const float* st = sst + s * 9;
            double p;
            if (k == 1) p = ((double)st[8] - lb * (double)st[3]) / b;
            else        p = log((double)st[k + 2]) - (double)k * lb;
            num += (6.0 * s - 15.0) * LN2 * p;   // n*q_s - qs
        }
        double den = 105.0 * LN2 * LN2;          // n*q2s - qs^2
        double aa  = (k == 1) ? 1.0 : 1.0 / (double)(k - 1);
        out[ch * 8 + t] = (float)(aa * num / den);
    }
}

extern "C" void kernel_launch(void* const* d_in, const int* in_sizes, int n_in,
                              void* d_out, int out_size, void* d_ws, size_t ws_size,
                              hipStream_t stream) {
    const float* img    = (const float*)d_in[0];
    const int*   bounds = (const int*)d_in[1];
    float*       out    = (float*)d_out;
    float*       ws     = (float*)d_ws;

    // ws layout (floats): part[6*36*256=55296] @0, l3map[6*4096=24576] @55296.
    float* part  = ws;
    float* l3map = ws + 55296;

    k_main<<<dim3(256, 6), 256, 0, stream>>>(img, part, l3map);
    k_fin<<<6, 512, 0, stream>>>(part, l3map, bounds, out);
}